// Round 3
// baseline (585.538 us; speedup 1.0000x reference)
//
#include <hip/hip_runtime.h>

#define NA    3
#define CP5   85
#define NC    80
#define NB    64
#define NG    52
#define GG    (NG * NG)        // 2704
#define NCELL (NB * GG)        // 173056
#define PLANE GG
#define CELLW (1.0f / 52.0f)

#define K2_BLOCKS 2048
#define K2_WAVES  (K2_BLOCKS * 4)   // 256 thr/block = 4 waves

// ws layout: float acc[8] @0  (0=coord 1=obj 2=cls 3=noobj)
//            int   cnt    @32
//            int   list[] @64
__global__ __launch_bounds__(256) void yolo_pass1(const float* __restrict__ pred,
                                                  const float* __restrict__ targ,
                                                  float* __restrict__ acc,
                                                  int* __restrict__ cnt,
                                                  int* __restrict__ list,
                                                  int list_cap) {
    int n = blockIdx.x * blockDim.x + threadIdx.x;
    float s_noobj = 0.f;
    if (n < NCELL) {
        int b = n / GG;
        int g = n - b * GG;
        const float* tb = targ + (size_t)b * 6 * PLANE + g;
        float tobj = tb[4 * PLANE];
        if (tobj == 1.0f) {
            int pos = atomicAdd(cnt, 1);
            if (pos < list_cap) list[pos] = n;
        } else {
            const float* pb = pred + (size_t)b * (NA * CP5) * PLANE + g;
            float c0 = pb[(0 * CP5 + 4) * PLANE];
            float c1 = pb[(1 * CP5 + 4) * PLANE];
            float c2 = pb[(2 * CP5 + 4) * PLANE];
            s_noobj = -(logf(1.f - c0) + logf(1.f - c1) + logf(1.f - c2));
        }
    }
    #pragma unroll
    for (int o = 32; o > 0; o >>= 1) s_noobj += __shfl_down(s_noobj, o);
    if ((threadIdx.x & 63) == 0 && s_noobj != 0.f) atomicAdd(&acc[3], s_noobj);
}

// one wave per obj cell; lanes cooperate on gathers + class reduction
__global__ __launch_bounds__(256) void yolo_pass2(const float* __restrict__ pred,
                                                  const float* __restrict__ targ,
                                                  float* __restrict__ acc,
                                                  const int* __restrict__ cnt,
                                                  const int* __restrict__ list,
                                                  int list_cap) {
    int gtid = blockIdx.x * blockDim.x + threadIdx.x;
    int wid  = gtid >> 6;
    int lane = threadIdx.x & 63;
    int count = *cnt;
    if (count > list_cap) count = list_cap;

    float a_coord = 0.f, a_obj = 0.f, a_cls = 0.f;

    for (int i = wid; i < count; i += K2_WAVES) {
        int n = list[i];                          // same addr all lanes: broadcast
        int b   = n / GG;
        int g   = n - b * GG;
        int row = g / NG;
        int col = g - row * NG;
        const float* pb = pred + (size_t)b * (NA * CP5) * PLANE + g;
        const float* tb = targ + (size_t)b * 6 * PLANE + g;

        // ---- gather target (6 lanes) + anchor xywh/conf (15 lanes) in parallel
        float tv = (lane < 6) ? tb[(size_t)lane * PLANE] : 0.f;
        float av = 0.f;
        if (lane < 15) {
            int a = lane / 5, k = lane - 5 * a;
            av = pb[((size_t)(a * CP5 + k)) * PLANE];
        }
        float tx = __shfl(tv, 0), ty = __shfl(tv, 1);
        float tw = __shfl(tv, 2), th = __shfl(tv, 3);
        int tcls = (int)__shfl(tv, 5);

        float colf = (float)col * CELLW, rowf = (float)row * CELLW;
        float bx1 = tx - tw * 0.5f, by1 = ty - th * 0.5f;
        float bx2 = tx + tw * 0.5f, by2 = ty + th * 0.5f;
        float area_b = (bx2 - bx1) * (by2 - by1);

        // all lanes redundantly compute the 3 IoUs from broadcasts (no divergence)
        float best_iou = -1e30f;
        int best = 0;
        float bpx = 0, bpy = 0, bpw = 0, bph = 0, bpc = 0;
        #pragma unroll
        for (int a = 0; a < NA; ++a) {
            float px = __shfl(av, 5 * a + 0) + colf;
            float py = __shfl(av, 5 * a + 1) + rowf;
            float pw = __shfl(av, 5 * a + 2);
            float ph = __shfl(av, 5 * a + 3);
            float pc = __shfl(av, 5 * a + 4);
            float ax1 = px - pw * 0.5f, ay1 = py - ph * 0.5f;
            float ax2 = px + pw * 0.5f, ay2 = py + ph * 0.5f;
            float iw = fmaxf(fminf(ax2, bx2) - fmaxf(ax1, bx1), 0.f);
            float ih = fmaxf(fminf(ay2, by2) - fmaxf(ay1, by1), 0.f);
            float inter  = iw * ih;
            float area_a = (ax2 - ax1) * (ay2 - ay1);
            float iou    = inter / (area_a + area_b - inter);
            if (iou > best_iou) {   // strict > = first-occurrence argmax (matches jnp.argmax)
                best_iou = iou; best = a;
                bpx = px; bpy = py; bpw = pw; bph = ph; bpc = pc;
            }
        }

        // ---- class channels of best anchor: lane-parallel gather
        const float* cls = pb + ((size_t)(best * CP5 + 5)) * PLANE;
        float x1 = cls[(size_t)lane * PLANE];                         // classes 0..63
        float x2 = (lane < 16) ? cls[(size_t)(64 + lane) * PLANE] : 0.f;
        // pred in (0.01,0.99) => sum(exp(x)) <= 80*e, safe without max-shift
        float psum = __expf(x1) + ((lane < 16) ? __expf(x2) : 0.f);
        #pragma unroll
        for (int o = 32; o > 0; o >>= 1) psum += __shfl_down(psum, o);
        // picked class logit
        float v1 = __shfl(x1, tcls & 63);
        float v2 = __shfl(x2, tcls & 63);
        float x_cls = (tcls < 64) ? v1 : v2;

        if (lane == 0) {
            float dx = bpx - tx, dy = bpy - ty;
            float dw = sqrtf(bpw) - sqrtf(tw);
            float dh = sqrtf(bph) - sqrtf(th);
            a_coord += dx * dx + dy * dy + dw * dw + dh * dh;
            a_obj   += -logf(bpc);
            a_cls   += logf(psum) - x_cls;
        }
    }

    if (lane == 0 && (a_coord != 0.f || a_obj != 0.f || a_cls != 0.f)) {
        atomicAdd(&acc[0], a_coord);
        atomicAdd(&acc[1], a_obj);
        atomicAdd(&acc[2], a_cls);
    }
}

__global__ void yolo_final(const float* __restrict__ acc, const int* __restrict__ cnt,
                           float* __restrict__ out) {
    float n_obj   = (float)(*cnt);
    float n_noobj = (float)NCELL - n_obj;
    out[0] = acc[0] / (2.f * n_obj)
           + acc[1] / n_obj
           + acc[2] / n_obj
           + acc[3] / (n_noobj * 3.f);
}

extern "C" void kernel_launch(void* const* d_in, const int* in_sizes, int n_in,
                              void* d_out, int out_size, void* d_ws, size_t ws_size,
                              hipStream_t stream) {
    const float* pred = (const float*)d_in[0];
    const float* targ = (const float*)d_in[1];
    float* out = (float*)d_out;

    float* acc  = (float*)d_ws;
    int*   cnt  = (int*)((char*)d_ws + 32);
    int*   list = (int*)((char*)d_ws + 64);
    int list_cap = (int)((ws_size - 64) / sizeof(int));

    hipMemsetAsync(d_ws, 0, 64, stream);
    yolo_pass1<<<dim3((NCELL + 255) / 256), dim3(256), 0, stream>>>(pred, targ, acc, cnt, list, list_cap);
    yolo_pass2<<<dim3(K2_BLOCKS), dim3(256), 0, stream>>>(pred, targ, acc, cnt, list, list_cap);
    yolo_final<<<1, 1, 0, stream>>>(acc, cnt, out);
}

// Round 5
// 239.888 us; speedup vs baseline: 2.4409x; 2.4409x over previous
//
#include <hip/hip_runtime.h>

#define NA    3
#define CP5   85
#define NC    80
#define NB    64
#define NG    52
#define GG    (NG * NG)        // 2704
#define NCELL (NB * GG)        // 173056
#define PLANE GG
#define CELLW (1.0f / 52.0f)

#define P1_BLOCKS (NCELL / 256)     // 676 exact
#define K2_BLOCKS 1024
#define K2_WAVES  (K2_BLOCKS * 4)   // 4096 waves

// ws layout:
//   @0    int   cnt
//   @64   float noobj_part[676]            (per pass1 block)
//   @2816 float obj_part[K2_BLOCKS]        (per pass2 block, combined term)
//   @6912 int   list[]                     (compacted obj-cell indices)
#define OFF_NOOBJ 64
#define OFF_OBJ   2816
#define OFF_LIST  6912

__global__ __launch_bounds__(256) void yolo_pass1(const float* __restrict__ pred,
                                                  const float* __restrict__ targ,
                                                  int* __restrict__ cnt,
                                                  int* __restrict__ list, int list_cap,
                                                  float* __restrict__ noobj_part) {
    __shared__ int   wcnt[4];
    __shared__ int   wpre[4];
    __shared__ float wno[4];
    __shared__ int   basep;
    int tid = threadIdx.x;
    int n = blockIdx.x * 256 + tid;            // grid is exact: no bound check
    int b = n / GG, g = n - b * GG;
    const float* tb = targ + (size_t)b * 6 * PLANE + g;
    float tobj = tb[4 * PLANE];
    bool isobj = (tobj == 1.0f);
    float s_noobj = 0.f;
    if (!isobj) {
        const float* pb = pred + (size_t)b * (NA * CP5) * PLANE + g;
        float c0 = pb[(0 * CP5 + 4) * PLANE];
        float c1 = pb[(1 * CP5 + 4) * PLANE];
        float c2 = pb[(2 * CP5 + 4) * PLANE];
        s_noobj = -(logf(1.f - c0) + logf(1.f - c1) + logf(1.f - c2));
    }
    unsigned long long ball = __ballot(isobj);
    int lane = tid & 63, w = tid >> 6;
    int within = __popcll(ball & ((1ull << lane) - 1ull));
    #pragma unroll
    for (int o = 32; o > 0; o >>= 1) s_noobj += __shfl_down(s_noobj, o);
    if (lane == 0) { wcnt[w] = (int)__popcll(ball); wno[w] = s_noobj; }
    __syncthreads();
    if (tid == 0) {
        int c0 = wcnt[0], c1 = wcnt[1], c2 = wcnt[2], c3 = wcnt[3];
        wpre[0] = 0; wpre[1] = c0; wpre[2] = c0 + c1; wpre[3] = c0 + c1 + c2;
        int tot = c0 + c1 + c2 + c3;
        basep = tot ? atomicAdd(cnt, tot) : 0;   // ONE contended atomic per block (676 total)
        noobj_part[blockIdx.x] = wno[0] + wno[1] + wno[2] + wno[3];
    }
    __syncthreads();
    if (isobj) {
        int pos = basep + wpre[w] + within;
        if (pos < list_cap) list[pos] = n;
    }
}

// one wave per obj cell; lanes cooperate on gathers + class reduction.
// Accumulation: NO atomics — one plain store per block.
__global__ __launch_bounds__(256) void yolo_pass2(const float* __restrict__ pred,
                                                  const float* __restrict__ targ,
                                                  const int* __restrict__ cnt,
                                                  const int* __restrict__ list, int list_cap,
                                                  float* __restrict__ obj_part) {
    __shared__ float bp[4];
    int gtid = blockIdx.x * blockDim.x + threadIdx.x;
    int wid  = gtid >> 6;
    int lane = threadIdx.x & 63;
    int w    = threadIdx.x >> 6;
    int count = *cnt;
    if (count > list_cap) count = list_cap;

    float a_sum = 0.f;   // lane 0 accumulates 0.5*coord + obj + cls

    for (int i = wid; i < count; i += K2_WAVES) {
        int n = list[i];                          // same addr all lanes: broadcast
        int b   = n / GG;
        int g   = n - b * GG;
        int row = g / NG;
        int col = g - row * NG;
        const float* pb = pred + (size_t)b * (NA * CP5) * PLANE + g;
        const float* tb = targ + (size_t)b * 6 * PLANE + g;

        // gather target (6 lanes) + anchor xywh/conf (15 lanes) in parallel
        float tv = (lane < 6) ? tb[(size_t)lane * PLANE] : 0.f;
        float av = 0.f;
        if (lane < 15) {
            int a = lane / 5, k = lane - 5 * a;
            av = pb[((size_t)(a * CP5 + k)) * PLANE];
        }
        float tx = __shfl(tv, 0), ty = __shfl(tv, 1);
        float tw = __shfl(tv, 2), th = __shfl(tv, 3);
        int tcls = (int)__shfl(tv, 5);

        float colf = (float)col * CELLW, rowf = (float)row * CELLW;
        float bx1 = tx - tw * 0.5f, by1 = ty - th * 0.5f;
        float bx2 = tx + tw * 0.5f, by2 = ty + th * 0.5f;
        float area_b = (bx2 - bx1) * (by2 - by1);

        float best_iou = -1e30f;
        int best = 0;
        float bpx = 0, bpy = 0, bpw = 0, bph = 0, bpc = 0;
        #pragma unroll
        for (int a = 0; a < NA; ++a) {
            float px = __shfl(av, 5 * a + 0) + colf;
            float py = __shfl(av, 5 * a + 1) + rowf;
            float pw = __shfl(av, 5 * a + 2);
            float ph = __shfl(av, 5 * a + 3);
            float pc = __shfl(av, 5 * a + 4);
            float ax1 = px - pw * 0.5f, ay1 = py - ph * 0.5f;
            float ax2 = px + pw * 0.5f, ay2 = py + ph * 0.5f;
            float iw = fmaxf(fminf(ax2, bx2) - fmaxf(ax1, bx1), 0.f);
            float ih = fmaxf(fminf(ay2, by2) - fmaxf(ay1, by1), 0.f);
            float inter  = iw * ih;
            float area_a = (ax2 - ax1) * (ay2 - ay1);
            float iou    = inter / (area_a + area_b - inter);
            if (iou > best_iou) {   // strict > = first-occurrence argmax (matches jnp.argmax)
                best_iou = iou; best = a;
                bpx = px; bpy = py; bpw = pw; bph = ph; bpc = pc;
            }
        }

        // class channels of best anchor: lane-parallel gather
        const float* cls = pb + ((size_t)(best * CP5 + 5)) * PLANE;
        float x1 = cls[(size_t)lane * PLANE];                         // classes 0..63
        float x2 = (lane < 16) ? cls[(size_t)(64 + lane) * PLANE] : 0.f;
        // pred in (0.01,0.99) => sum(exp(x)) <= 80*e, safe without max-shift
        float psum = __expf(x1) + ((lane < 16) ? __expf(x2) : 0.f);
        #pragma unroll
        for (int o = 32; o > 0; o >>= 1) psum += __shfl_down(psum, o);
        float v1 = __shfl(x1, tcls & 63);
        float v2 = __shfl(x2, tcls & 63);
        float x_cls = (tcls < 64) ? v1 : v2;

        if (lane == 0) {
            float dx = bpx - tx, dy = bpy - ty;
            float dw = sqrtf(bpw) - sqrtf(tw);
            float dh = sqrtf(bph) - sqrtf(th);
            float coord = dx * dx + dy * dy + dw * dw + dh * dh;
            a_sum += 0.5f * coord + (-logf(bpc)) + (logf(psum) - x_cls);
        }
    }

    if (lane == 0) bp[w] = a_sum;
    __syncthreads();
    if (threadIdx.x == 0) obj_part[blockIdx.x] = bp[0] + bp[1] + bp[2] + bp[3];
}

// MUST be launched with 256 threads (Round 4 bug: was launched with 1 thread,
// summing only every 256th partial + reading uninitialized LDS).
__global__ __launch_bounds__(256) void yolo_final(const int* __restrict__ cnt,
                                                  const float* __restrict__ noobj_part,
                                                  const float* __restrict__ obj_part,
                                                  float* __restrict__ out) {
    __shared__ float ao[4], an[4];
    float s_obj = 0.f, s_no = 0.f;
    for (int i = threadIdx.x; i < K2_BLOCKS; i += blockDim.x) s_obj += obj_part[i];
    for (int i = threadIdx.x; i < P1_BLOCKS; i += blockDim.x) s_no += noobj_part[i];
    #pragma unroll
    for (int o = 32; o > 0; o >>= 1) {
        s_obj += __shfl_down(s_obj, o);
        s_no  += __shfl_down(s_no, o);
    }
    int lane = threadIdx.x & 63, w = threadIdx.x >> 6;
    if (lane == 0) { ao[w] = s_obj; an[w] = s_no; }
    __syncthreads();
    if (threadIdx.x == 0) {
        float n_obj = (float)(*cnt);
        float obj   = ao[0] + ao[1] + ao[2] + ao[3];
        float no    = an[0] + an[1] + an[2] + an[3];
        out[0] = obj / n_obj + no / (3.f * ((float)NCELL - n_obj));
    }
}

extern "C" void kernel_launch(void* const* d_in, const int* in_sizes, int n_in,
                              void* d_out, int out_size, void* d_ws, size_t ws_size,
                              hipStream_t stream) {
    const float* pred = (const float*)d_in[0];
    const float* targ = (const float*)d_in[1];
    float* out = (float*)d_out;

    int*   cnt        = (int*)d_ws;
    float* noobj_part = (float*)((char*)d_ws + OFF_NOOBJ);
    float* obj_part   = (float*)((char*)d_ws + OFF_OBJ);
    int*   list       = (int*)((char*)d_ws + OFF_LIST);
    int list_cap = (int)((ws_size - OFF_LIST) / sizeof(int));

    hipMemsetAsync(d_ws, 0, 64, stream);  // zero cnt only; partials are fully overwritten
    yolo_pass1<<<dim3(P1_BLOCKS), dim3(256), 0, stream>>>(pred, targ, cnt, list, list_cap, noobj_part);
    yolo_pass2<<<dim3(K2_BLOCKS), dim3(256), 0, stream>>>(pred, targ, cnt, list, list_cap, obj_part);
    yolo_final<<<1, 256, 0, stream>>>(cnt, noobj_part, obj_part, out);
}

// Round 6
// 227.517 us; speedup vs baseline: 2.5736x; 1.0544x over previous
//
#include <hip/hip_runtime.h>

#define NA    3
#define CP5   85
#define NC    80
#define NB    64
#define NG    52
#define GG    (NG * NG)        // 2704
#define NCELL (NB * GG)        // 173056
#define PLANE GG
#define CELLW (1.0f / 52.0f)

#define MBLOCKS (NCELL / 256)  // 676 exact

// ws layout: float obj_part[676] @0 ; float noobj_part[676] @2816 ; float cnt_part[676] @5632
#define OFF_NO  2816
#define OFF_CNT 5632

// One kernel: per block, noobj term for its 256 cells + block-local compaction of
// obj cells into LDS, then the 4 waves process them wave-cooperatively.
// Zero atomics, zero global intermediates besides 3 per-block partials.
__global__ __launch_bounds__(256) void yolo_fused(const float* __restrict__ pred,
                                                  const float* __restrict__ targ,
                                                  float* __restrict__ obj_part,
                                                  float* __restrict__ noobj_part,
                                                  float* __restrict__ cnt_part) {
    __shared__ unsigned short lst[256];
    __shared__ int   wcnt[4];
    __shared__ float wno[4];
    __shared__ float wobj[4];

    int tid  = threadIdx.x;
    int lane = tid & 63;
    int w    = tid >> 6;

    // ---- per-cell noobj + obj detection (grid exact, no bounds check)
    int n0 = blockIdx.x * 256 + tid;
    int b0 = n0 / GG, g0 = n0 - b0 * GG;
    const float* tb0 = targ + (size_t)b0 * 6 * PLANE + g0;
    float tobj = tb0[4 * PLANE];
    bool isobj = (tobj == 1.0f);
    float s_noobj = 0.f;
    if (!isobj) {
        const float* pb0 = pred + (size_t)b0 * (NA * CP5) * PLANE + g0;
        float c0 = pb0[(0 * CP5 + 4) * PLANE];
        float c1 = pb0[(1 * CP5 + 4) * PLANE];
        float c2 = pb0[(2 * CP5 + 4) * PLANE];
        s_noobj = -(logf(1.f - c0) + logf(1.f - c1) + logf(1.f - c2));
    }
    unsigned long long ball = __ballot(isobj);
    int within = __popcll(ball & ((1ull << lane) - 1ull));
    #pragma unroll
    for (int o = 32; o > 0; o >>= 1) s_noobj += __shfl_down(s_noobj, o);
    if (lane == 0) { wcnt[w] = (int)__popcll(ball); wno[w] = s_noobj; }
    __syncthreads();
    int c0n = wcnt[0], c1n = wcnt[1], c2n = wcnt[2], c3n = wcnt[3];
    int wbase = (w > 0 ? c0n : 0) + (w > 1 ? c1n : 0) + (w > 2 ? c2n : 0);
    int tot = c0n + c1n + c2n + c3n;          // <= 256 == lst capacity
    if (isobj) lst[wbase + within] = (unsigned short)tid;
    __syncthreads();

    // ---- obj cells: 4 waves stride the block-local list (validated pass2 body)
    float a_sum = 0.f;   // lane 0: 0.5*coord + obj + cls
    for (int j = w; j < tot; j += 4) {
        int n = blockIdx.x * 256 + (int)lst[j];   // uniform LDS read: broadcast
        int b   = n / GG;
        int g   = n - b * GG;
        int row = g / NG;
        int col = g - row * NG;
        const float* pb = pred + (size_t)b * (NA * CP5) * PLANE + g;
        const float* tb = targ + (size_t)b * 6 * PLANE + g;

        // gather target (6 lanes) + anchor xywh/conf (15 lanes) in parallel
        float tv = (lane < 6) ? tb[(size_t)lane * PLANE] : 0.f;
        float av = 0.f;
        if (lane < 15) {
            int a = lane / 5, k = lane - 5 * a;
            av = pb[((size_t)(a * CP5 + k)) * PLANE];
        }
        float tx = __shfl(tv, 0), ty = __shfl(tv, 1);
        float tw = __shfl(tv, 2), th = __shfl(tv, 3);
        int tcls = (int)__shfl(tv, 5);

        float colf = (float)col * CELLW, rowf = (float)row * CELLW;
        float bx1 = tx - tw * 0.5f, by1 = ty - th * 0.5f;
        float bx2 = tx + tw * 0.5f, by2 = ty + th * 0.5f;
        float area_b = (bx2 - bx1) * (by2 - by1);

        float best_iou = -1e30f;
        int best = 0;
        float bpx = 0, bpy = 0, bpw = 0, bph = 0, bpc = 0;
        #pragma unroll
        for (int a = 0; a < NA; ++a) {
            float px = __shfl(av, 5 * a + 0) + colf;
            float py = __shfl(av, 5 * a + 1) + rowf;
            float pw = __shfl(av, 5 * a + 2);
            float ph = __shfl(av, 5 * a + 3);
            float pc = __shfl(av, 5 * a + 4);
            float ax1 = px - pw * 0.5f, ay1 = py - ph * 0.5f;
            float ax2 = px + pw * 0.5f, ay2 = py + ph * 0.5f;
            float iw = fmaxf(fminf(ax2, bx2) - fmaxf(ax1, bx1), 0.f);
            float ih = fmaxf(fminf(ay2, by2) - fmaxf(ay1, by1), 0.f);
            float inter  = iw * ih;
            float area_a = (ax2 - ax1) * (ay2 - ay1);
            float iou    = inter / (area_a + area_b - inter);
            if (iou > best_iou) {   // strict > = first-occurrence argmax (matches jnp.argmax)
                best_iou = iou; best = a;
                bpx = px; bpy = py; bpw = pw; bph = ph; bpc = pc;
            }
        }

        // class channels of best anchor: lane-parallel gather
        const float* cls = pb + ((size_t)(best * CP5 + 5)) * PLANE;
        float x1 = cls[(size_t)lane * PLANE];
        float x2 = (lane < 16) ? cls[(size_t)(64 + lane) * PLANE] : 0.f;
        // pred in (0.01,0.99) => sum(exp(x)) <= 80*e, safe without max-shift
        float psum = __expf(x1) + ((lane < 16) ? __expf(x2) : 0.f);
        #pragma unroll
        for (int o = 32; o > 0; o >>= 1) psum += __shfl_down(psum, o);
        float v1 = __shfl(x1, tcls & 63);
        float v2 = __shfl(x2, tcls & 63);
        float x_cls = (tcls < 64) ? v1 : v2;

        if (lane == 0) {
            float dx = bpx - tx, dy = bpy - ty;
            float dw = sqrtf(bpw) - sqrtf(tw);
            float dh = sqrtf(bph) - sqrtf(th);
            float coord = dx * dx + dy * dy + dw * dw + dh * dh;
            a_sum += 0.5f * coord + (-logf(bpc)) + (logf(psum) - x_cls);
        }
    }

    if (lane == 0) wobj[w] = a_sum;
    __syncthreads();
    if (tid == 0) {
        obj_part[blockIdx.x]   = wobj[0] + wobj[1] + wobj[2] + wobj[3];
        noobj_part[blockIdx.x] = wno[0] + wno[1] + wno[2] + wno[3];
        cnt_part[blockIdx.x]   = (float)tot;   // exact: integer <= 256 in fp32
    }
}

// MUST be launched with 256 threads.
__global__ __launch_bounds__(256) void yolo_final(const float* __restrict__ obj_part,
                                                  const float* __restrict__ noobj_part,
                                                  const float* __restrict__ cnt_part,
                                                  float* __restrict__ out) {
    __shared__ float ao[4], an[4], ac[4];
    float s_obj = 0.f, s_no = 0.f, s_c = 0.f;
    for (int i = threadIdx.x; i < MBLOCKS; i += blockDim.x) {
        s_obj += obj_part[i];
        s_no  += noobj_part[i];
        s_c   += cnt_part[i];
    }
    #pragma unroll
    for (int o = 32; o > 0; o >>= 1) {
        s_obj += __shfl_down(s_obj, o);
        s_no  += __shfl_down(s_no, o);
        s_c   += __shfl_down(s_c, o);
    }
    int lane = threadIdx.x & 63, w = threadIdx.x >> 6;
    if (lane == 0) { ao[w] = s_obj; an[w] = s_no; ac[w] = s_c; }
    __syncthreads();
    if (threadIdx.x == 0) {
        float obj   = ao[0] + ao[1] + ao[2] + ao[3];
        float no    = an[0] + an[1] + an[2] + an[3];
        float n_obj = ac[0] + ac[1] + ac[2] + ac[3];
        out[0] = obj / n_obj + no / (3.f * ((float)NCELL - n_obj));
    }
}

extern "C" void kernel_launch(void* const* d_in, const int* in_sizes, int n_in,
                              void* d_out, int out_size, void* d_ws, size_t ws_size,
                              hipStream_t stream) {
    const float* pred = (const float*)d_in[0];
    const float* targ = (const float*)d_in[1];
    float* out = (float*)d_out;

    float* obj_part   = (float*)d_ws;
    float* noobj_part = (float*)((char*)d_ws + OFF_NO);
    float* cnt_part   = (float*)((char*)d_ws + OFF_CNT);

    // no memset needed: every partial slot is unconditionally overwritten
    yolo_fused<<<dim3(MBLOCKS), dim3(256), 0, stream>>>(pred, targ, obj_part, noobj_part, cnt_part);
    yolo_final<<<1, 256, 0, stream>>>(obj_part, noobj_part, cnt_part, out);
}